// Round 14
// baseline (997.055 us; speedup 1.0000x reference)
//
#include <hip/hip_runtime.h>
#include <math.h>

#define N_NODES 50000
#define F_IN    512
#define HDIM    256
#define L_OUT   52
#define E_EDGES 1600000
#define NB1     391      // ceil(N/128) level-1 buckets (dst>>7)
#define EB      2048     // edges per chunk
#define NBLK    782      // ceil(E/EB)

typedef short short8 __attribute__((ext_vector_type(8)));
typedef unsigned short u16x8 __attribute__((ext_vector_type(8)));
typedef float f32x4 __attribute__((ext_vector_type(4)));
typedef float f32x2 __attribute__((ext_vector_type(2)));

__device__ __forceinline__ float bf2f(unsigned short u) {
    unsigned int x = ((unsigned int)u) << 16;
    return __builtin_bit_cast(float, x);
}
__device__ __forceinline__ unsigned short f2bf(float f) {
    unsigned int u = __builtin_bit_cast(unsigned int, f);
    return (unsigned short)((u + 0x7fffu + ((u >> 16) & 1u)) >> 16);
}
__device__ __forceinline__ unsigned char f2fp8(float f) {
    int pk = __builtin_amdgcn_cvt_pk_fp8_f32(f, 0.f, 0, false);
    return (unsigned char)(pk & 0xff);
}
__device__ __forceinline__ void gload16(const unsigned short* g, unsigned short* l) {
    __builtin_amdgcn_global_load_lds(
        (const __attribute__((address_space(1))) unsigned int*)(g),
        (__attribute__((address_space(3))) unsigned int*)(l), 16, 0, 0);
}

// ---------------- CSR build: atomic-free two-level counting sort ----------

__global__ __launch_bounds__(256) void k_hist(const int* __restrict__ d1, const int* __restrict__ d2,
                                              int* __restrict__ h1, int* __restrict__ h2, int E) {
    const int* D = blockIdx.y ? d2 : d1;
    int* H = blockIdx.y ? h2 : h1;
    __shared__ int h[NB1];
    for (int t = threadIdx.x; t < NB1; t += 256) h[t] = 0;
    __syncthreads();
    int base = blockIdx.x * EB;
#pragma unroll
    for (int k = 0; k < 8; k++) {
        int e = base + k * 256 + threadIdx.x;
        if (e < E) atomicAdd(&h[D[e] >> 7], 1);   // LDS atomic
    }
    __syncthreads();
    for (int t = threadIdx.x; t < NB1; t += 256)
        H[(size_t)t * NBLK + blockIdx.x] = h[t];
}

__global__ __launch_bounds__(256) void k_scanb(int* __restrict__ h1, int* __restrict__ h2,
                                               int* __restrict__ t1, int* __restrict__ t2) {
    int* H = blockIdx.y ? h2 : h1;
    int* T = blockIdx.y ? t2 : t1;
    int b = blockIdx.x;
    __shared__ int s[256];
    int carry = 0;
    for (int base = 0; base < NBLK; base += 256) {
        int i = base + threadIdx.x;
        int v = (i < NBLK) ? H[(size_t)b * NBLK + i] : 0;
        s[threadIdx.x] = v;
        __syncthreads();
        for (int off = 1; off < 256; off <<= 1) {
            int t = (threadIdx.x >= off) ? s[threadIdx.x - off] : 0;
            __syncthreads();
            s[threadIdx.x] += t;
            __syncthreads();
        }
        if (i < NBLK) H[(size_t)b * NBLK + i] = carry + s[threadIdx.x] - v;
        int ct = s[255];
        __syncthreads();
        carry += ct;
    }
    if (threadIdx.x == 0) T[b] = carry;
}

__global__ __launch_bounds__(512) void k_bstart(const int* __restrict__ t1, const int* __restrict__ t2,
                                                int* __restrict__ b1, int* __restrict__ b2,
                                                int* __restrict__ rp1, int* __restrict__ rp2,
                                                int N, int E) {
    const int* T = blockIdx.y ? t2 : t1;
    int* BS = blockIdx.y ? b2 : b1;
    int* RP = blockIdx.y ? rp2 : rp1;
    __shared__ int s[512];
    int v = (threadIdx.x < NB1) ? T[threadIdx.x] : 0;
    s[threadIdx.x] = v;
    __syncthreads();
    for (int off = 1; off < 512; off <<= 1) {
        int t = (threadIdx.x >= off) ? s[threadIdx.x - off] : 0;
        __syncthreads();
        s[threadIdx.x] += t;
        __syncthreads();
    }
    if (threadIdx.x < NB1) BS[threadIdx.x] = s[threadIdx.x] - v;
    if (threadIdx.x == 0) { BS[NB1] = E; RP[N] = E; }
}

__global__ __launch_bounds__(256) void k_scatter(const int* __restrict__ s1, const int* __restrict__ d1,
                                                 const int* __restrict__ s2, const int* __restrict__ d2,
                                                 const int* __restrict__ h1, const int* __restrict__ h2,
                                                 const int* __restrict__ b1, const int* __restrict__ b2,
                                                 unsigned int* __restrict__ r1, unsigned int* __restrict__ r2,
                                                 int E) {
    int br = blockIdx.y;
    const int* S = br ? s2 : s1;
    const int* D = br ? d2 : d1;
    const int* H = br ? h2 : h1;
    const int* BS = br ? b2 : b1;
    unsigned int* R = br ? r2 : r1;
    __shared__ int cur[NB1];
    for (int t = threadIdx.x; t < NB1; t += 256)
        cur[t] = BS[t] + H[(size_t)t * NBLK + blockIdx.x];
    __syncthreads();
    int base = blockIdx.x * EB;
#pragma unroll
    for (int k = 0; k < 8; k++) {
        int e = base + k * 256 + threadIdx.x;
        if (e < E) {
            int d = D[e];
            int p = atomicAdd(&cur[d >> 7], 1);   // LDS atomic, block-exclusive range
            R[p] = (unsigned int)(S[e] & 0xFFFF) | ((unsigned int)d << 16);
        }
    }
}

__global__ __launch_bounds__(256) void k_sort(const unsigned int* __restrict__ r1,
                                              const unsigned int* __restrict__ r2,
                                              const int* __restrict__ b1, const int* __restrict__ b2,
                                              int* __restrict__ c1, int* __restrict__ c2,
                                              int* __restrict__ rp1, int* __restrict__ rp2,
                                              unsigned short* __restrict__ col1,
                                              unsigned short* __restrict__ col2, int N) {
    int br = blockIdx.y;
    const unsigned int* R = br ? r2 : r1;
    const int* BS = br ? b2 : b1;
    int* CNT = br ? c2 : c1;
    int* RP = br ? rp2 : rp1;
    unsigned short* COL = br ? col2 : col1;
    int b = blockIdx.x;
    int s = BS[b], sz = BS[b + 1] - s;
    __shared__ int h[128], sc[128], cur[128];
    if (threadIdx.x < 128) h[threadIdx.x] = 0;
    __syncthreads();
    for (int i = s + threadIdx.x; i < s + sz; i += 256)
        atomicAdd(&h[(R[i] >> 16) & 127], 1);
    __syncthreads();
    if (threadIdx.x < 128) sc[threadIdx.x] = h[threadIdx.x];
    __syncthreads();
    for (int off = 1; off < 128; off <<= 1) {
        int t = 0;
        if (threadIdx.x < 128 && threadIdx.x >= off) t = sc[threadIdx.x - off];
        __syncthreads();
        if (threadIdx.x < 128) sc[threadIdx.x] += t;
        __syncthreads();
    }
    if (threadIdx.x < 128) {
        int excl = sc[threadIdx.x] - h[threadIdx.x];
        cur[threadIdx.x] = excl;
        int node = b * 128 + threadIdx.x;
        if (node < N) { CNT[node] = h[threadIdx.x]; RP[node] = s + excl; }
    }
    __syncthreads();
    for (int i = s + threadIdx.x; i < s + sz; i += 256) {
        unsigned int r = R[i];
        int low = (r >> 16) & 127;
        int p = atomicAdd(&cur[low], 1);          // LDS atomic
        COL[s + p] = (unsigned short)(r & 0xFFFFu);
    }
}

// ------------------------------------------------------------- conversions

__global__ void k_dinv2(const int* __restrict__ c1, const int* __restrict__ c2,
                        float* __restrict__ v1, float* __restrict__ v2, int n) {
    int i = blockIdx.x * blockDim.x + threadIdx.x;
    if (i < n) v1[i] = rsqrtf((float)(c1[i] + 1));
    else if (i < 2 * n) v2[i - n] = rsqrtf((float)(c2[i - n] + 1));
}

// fp32 -> bf16, 32B read / 16B write per thread
__global__ void k_f2b2(const float* __restrict__ x1, const float* __restrict__ x2,
                       unsigned short* __restrict__ o1, unsigned short* __restrict__ o2,
                       int n8) {
    int i = blockIdx.x * blockDim.x + threadIdx.x;
    int stride = gridDim.x * blockDim.x;
    int tot = 2 * n8;
    for (; i < tot; i += stride) {
        int br = i >= n8;
        int e = br ? i - n8 : i;
        const float4* src = (const float4*)(br ? x2 : x1);
        float4 a = src[2 * e], b = src[2 * e + 1];
        u16x8 o;
        o[0] = f2bf(a.x); o[1] = f2bf(a.y); o[2] = f2bf(a.z); o[3] = f2bf(a.w);
        o[4] = f2bf(b.x); o[5] = f2bf(b.y); o[6] = f2bf(b.z); o[7] = f2bf(b.w);
        ((u16x8*)(br ? o2 : o1))[e] = o;
    }
}

struct WDesc { const float* in; unsigned short* out; int K; int N; int Npad; };
struct WPack { WDesc d[10]; };

__global__ void k_wconv(WPack p) {
    WDesc w = p.d[blockIdx.y];
    int total = w.K * w.Npad;
    int idx = blockIdx.x * 256 + threadIdx.x;
    if (idx >= total) return;
    int n = idx / w.K, k = idx - n * w.K;
    w.out[idx] = (n < w.N) ? f2bf(w.in[(size_t)k * w.N + n]) : (unsigned short)0;
}

// ------- aggregation: persistent waves (grid-stride over nodes), lane-halves
//         = even/odd neighbor streams, 16-deep 8B fp8 gathers.

__global__ __launch_bounds__(256) void k_agg(const unsigned char* __restrict__ g,
                      const int* __restrict__ rowptr,
                      const unsigned short* __restrict__ col,
                      const float* __restrict__ dinv,
                      const float* __restrict__ bias, unsigned short* __restrict__ out,
                      int n, int do_relu) {
    int gtid = blockIdx.x * blockDim.x + threadIdx.x;
    int wid0 = gtid >> 6;
    int wstride = (gridDim.x * blockDim.x) >> 6;
    int lane = threadIdx.x & 63;
    int half = lane >> 5;   // even/odd neighbor stream
    int fl = lane & 31;     // 8B slice of the 256B fp8 row

    for (int wid = wid0; wid < n; wid += wstride) {
        float di = dinv[wid];
        float a[8];
#pragma unroll
        for (int k = 0; k < 8; k++) a[k] = 0.f;

        int r0 = rowptr[wid], r1 = rowptr[wid + 1];
        int base = r0;

        for (; base + 32 <= r1; base += 32) {
            int c[16]; float w[16]; uint2 v[16];
#pragma unroll
            for (int t = 0; t < 16; t++) c[t] = col[base + 2 * t + half];
#pragma unroll
            for (int t = 0; t < 16; t++) w[t] = dinv[c[t]];
#pragma unroll
            for (int t = 0; t < 16; t++)
                v[t] = ((const uint2*)(g + (size_t)c[t] * HDIM))[fl];
#pragma unroll
            for (int t = 0; t < 16; t++) {
                float wt = w[t] * di;
                f32x2 p0 = __builtin_amdgcn_cvt_pk_f32_fp8((int)v[t].x, false);
                f32x2 p1 = __builtin_amdgcn_cvt_pk_f32_fp8((int)v[t].x, true);
                f32x2 p2 = __builtin_amdgcn_cvt_pk_f32_fp8((int)v[t].y, false);
                f32x2 p3 = __builtin_amdgcn_cvt_pk_f32_fp8((int)v[t].y, true);
                a[0] = fmaf(p0[0], wt, a[0]); a[1] = fmaf(p0[1], wt, a[1]);
                a[2] = fmaf(p1[0], wt, a[2]); a[3] = fmaf(p1[1], wt, a[3]);
                a[4] = fmaf(p2[0], wt, a[4]); a[5] = fmaf(p2[1], wt, a[5]);
                a[6] = fmaf(p3[0], wt, a[6]); a[7] = fmaf(p3[1], wt, a[7]);
            }
        }
        for (; base + 16 <= r1; base += 16) {
            int c[8]; float w[8]; uint2 v[8];
#pragma unroll
            for (int t = 0; t < 8; t++) c[t] = col[base + 2 * t + half];
#pragma unroll
            for (int t = 0; t < 8; t++) w[t] = dinv[c[t]];
#pragma unroll
            for (int t = 0; t < 8; t++)
                v[t] = ((const uint2*)(g + (size_t)c[t] * HDIM))[fl];
#pragma unroll
            for (int t = 0; t < 8; t++) {
                float wt = w[t] * di;
                f32x2 p0 = __builtin_amdgcn_cvt_pk_f32_fp8((int)v[t].x, false);
                f32x2 p1 = __builtin_amdgcn_cvt_pk_f32_fp8((int)v[t].x, true);
                f32x2 p2 = __builtin_amdgcn_cvt_pk_f32_fp8((int)v[t].y, false);
                f32x2 p3 = __builtin_amdgcn_cvt_pk_f32_fp8((int)v[t].y, true);
                a[0] = fmaf(p0[0], wt, a[0]); a[1] = fmaf(p0[1], wt, a[1]);
                a[2] = fmaf(p1[0], wt, a[2]); a[3] = fmaf(p1[1], wt, a[3]);
                a[4] = fmaf(p2[0], wt, a[4]); a[5] = fmaf(p2[1], wt, a[5]);
                a[6] = fmaf(p3[0], wt, a[6]); a[7] = fmaf(p3[1], wt, a[7]);
            }
        }
        if (base < r1) {  // remainder 1..15, zero-weight padding
            int c[8]; float w[8]; uint2 v[8];
#pragma unroll
            for (int t = 0; t < 8; t++) {
                int idx = base + 2 * t + half;
                int ok = idx < r1;
                c[t] = col[ok ? idx : r0];
                w[t] = ok ? dinv[c[t]] : 0.f;
            }
#pragma unroll
            for (int t = 0; t < 8; t++)
                v[t] = ((const uint2*)(g + (size_t)c[t] * HDIM))[fl];
#pragma unroll
            for (int t = 0; t < 8; t++) {
                float wt = w[t] * di;
                f32x2 p0 = __builtin_amdgcn_cvt_pk_f32_fp8((int)v[t].x, false);
                f32x2 p1 = __builtin_amdgcn_cvt_pk_f32_fp8((int)v[t].x, true);
                f32x2 p2 = __builtin_amdgcn_cvt_pk_f32_fp8((int)v[t].y, false);
                f32x2 p3 = __builtin_amdgcn_cvt_pk_f32_fp8((int)v[t].y, true);
                a[0] = fmaf(p0[0], wt, a[0]); a[1] = fmaf(p0[1], wt, a[1]);
                a[2] = fmaf(p1[0], wt, a[2]); a[3] = fmaf(p1[1], wt, a[3]);
                a[4] = fmaf(p2[0], wt, a[4]); a[5] = fmaf(p2[1], wt, a[5]);
                a[6] = fmaf(p3[0], wt, a[6]); a[7] = fmaf(p3[1], wt, a[7]);
            }
        }

#pragma unroll
        for (int k = 0; k < 8; k++) a[k] += __shfl_xor(a[k], 32);

        float w0 = di * di;
        uint2 sv = ((const uint2*)(g + (size_t)wid * HDIM))[fl];
        f32x2 s0 = __builtin_amdgcn_cvt_pk_f32_fp8((int)sv.x, false);
        f32x2 s1 = __builtin_amdgcn_cvt_pk_f32_fp8((int)sv.x, true);
        f32x2 s2 = __builtin_amdgcn_cvt_pk_f32_fp8((int)sv.y, false);
        f32x2 s3 = __builtin_amdgcn_cvt_pk_f32_fp8((int)sv.y, true);
        float sf[8] = {s0[0], s0[1], s1[0], s1[1], s2[0], s2[1], s3[0], s3[1]};
        u16x8 o;
#pragma unroll
        for (int k = 0; k < 8; k++) {
            float x = fmaf(sf[k], w0, a[k]) + bias[fl * 8 + k];
            if (do_relu) x = fmaxf(x, 0.f);
            o[k] = f2bf(x);
        }
        if (half == 0)
            ((u16x8*)(out + (size_t)wid * HDIM))[fl] = o;
    }
}

// --------------------------------------------------- bf16 MFMA GEMM 128x128
// EPI 0: raw -> fp8 C.  EPI 1: bias+relu -> bf16.  EPI 2: bias+sigmoid -> fp32.

template <int EPI>
__global__ __launch_bounds__(256) void k_gemm(const unsigned short* __restrict__ A,
                                              const unsigned short* __restrict__ Bt,
                                              const float* __restrict__ bias,
                                              void* __restrict__ Cout,
                                              int M, int K, int Nc) {
    __shared__ __align__(16) unsigned short As[128 * 32];
    __shared__ __align__(16) unsigned short Bs[128 * 32];
    int tid = threadIdx.x;
    int wid = tid >> 6, lane = tid & 63;
    int wr = wid >> 1, wc = wid & 1;
    int mb = blockIdx.y * 128, nb = blockIdx.x * 128;

    int sr = tid >> 2;
    int ssl = (tid & 3) ^ ((sr >> 1) & 3);
    int ar0 = mb + sr;      if (ar0 > M - 1) ar0 = M - 1;
    int ar1 = mb + sr + 64; if (ar1 > M - 1) ar1 = M - 1;
    const unsigned short* gA0 = A + (size_t)ar0 * K + ssl * 8;
    const unsigned short* gA1 = A + (size_t)ar1 * K + ssl * 8;
    const unsigned short* gB0 = Bt + (size_t)(nb + sr) * K + ssl * 8;
    const unsigned short* gB1 = Bt + (size_t)(nb + sr + 64) * K + ssl * 8;
    unsigned short* ldsA = As + tid * 8;
    unsigned short* ldsB = Bs + tid * 8;

    f32x4 acc[4][4];
#pragma unroll
    for (int m = 0; m < 4; m++)
#pragma unroll
        for (int n = 0; n < 4; n++) acc[m][n] = (f32x4){0.f, 0.f, 0.f, 0.f};

    int l15 = lane & 15, ks = lane >> 4;

    for (int k0 = 0; k0 < K; k0 += 32) {
        gload16(gA0 + k0, ldsA);
        gload16(gA1 + k0, ldsA + 2048);
        gload16(gB0 + k0, ldsB);
        gload16(gB1 + k0, ldsB + 2048);
        __syncthreads();

        short8 af[4], bfr[4];
#pragma unroll
        for (int m = 0; m < 4; m++) {
            int row = wr * 64 + m * 16 + l15;
            int slot = ks ^ ((row >> 1) & 3);
            af[m] = *(const short8*)((const char*)As + row * 64 + slot * 16);
        }
#pragma unroll
        for (int n = 0; n < 4; n++) {
            int row = wc * 64 + n * 16 + l15;
            int slot = ks ^ ((row >> 1) & 3);
            bfr[n] = *(const short8*)((const char*)Bs + row * 64 + slot * 16);
        }
#pragma unroll
        for (int m = 0; m < 4; m++)
#pragma unroll
            for (int n = 0; n < 4; n++)
                acc[m][n] = __builtin_amdgcn_mfma_f32_16x16x32_bf16(af[m], bfr[n], acc[m][n], 0, 0, 0);
        __syncthreads();
    }

    int lq = lane >> 4;
#pragma unroll
    for (int m = 0; m < 4; m++) {
#pragma unroll
        for (int n = 0; n < 4; n++) {
            int gcol = nb + wc * 64 + n * 16 + l15;
#pragma unroll
            for (int r = 0; r < 4; r++) {
                int grow = mb + wr * 64 + m * 16 + lq * 4 + r;
                if (grow >= M) continue;
                float v = acc[m][n][r];
                if (EPI == 0) {
                    ((unsigned char*)Cout)[(size_t)grow * Nc + gcol] = f2fp8(v);
                } else if (EPI == 1) {
                    v += bias[gcol];
                    v = fmaxf(v, 0.f);
                    ((unsigned short*)Cout)[(size_t)grow * Nc + gcol] = f2bf(v);
                } else {
                    if (gcol < Nc) {
                        v += bias[gcol];
                        v = 1.f / (1.f + expf(-v));
                        ((float*)Cout)[(size_t)grow * Nc + gcol] = v;
                    }
                }
            }
        }
    }
}

// ------------------------------------------------------------- gate fusion

__global__ void k_gate(const unsigned short* __restrict__ h1, const unsigned short* __restrict__ h2,
                       const float* __restrict__ w1, const float* __restrict__ w1b,
                       const float* __restrict__ w2, const float* __restrict__ w2b,
                       unsigned short* __restrict__ m, int n) {
    int gtid = blockIdx.x * blockDim.x + threadIdx.x;
    int wid = gtid >> 6;
    int lane = threadIdx.x & 63;
    if (wid >= n) return;
    ushort4 av = ((const ushort4*)(h1 + (size_t)wid * HDIM))[lane];
    ushort4 bv = ((const ushort4*)(h2 + (size_t)wid * HDIM))[lane];
    float4 wa = ((const float4*)w1)[lane];
    float4 wb = ((const float4*)w2)[lane];
    float a0 = bf2f(av.x), a1 = bf2f(av.y), a2 = bf2f(av.z), a3 = bf2f(av.w);
    float b0 = bf2f(bv.x), b1 = bf2f(bv.y), b2 = bf2f(bv.z), b3 = bf2f(bv.w);
    float d1 = a0 * wa.x + a1 * wa.y + a2 * wa.z + a3 * wa.w;
    float d2 = b0 * wb.x + b1 * wb.y + b2 * wb.z + b3 * wb.w;
    for (int off = 32; off > 0; off >>= 1) {
        d1 += __shfl_xor(d1, off);
        d2 += __shfl_xor(d2, off);
    }
    float f1 = 1.f / (1.f + expf(-(d1 + w1b[0])));
    float f2 = 1.f / (1.f + expf(-(d2 + w2b[0])));
    float f = f1 / (f1 + f2);
    ushort4 o;
    o.x = f2bf(f * a0 + (1.f - f) * b0);
    o.y = f2bf(f * a1 + (1.f - f) * b1);
    o.z = f2bf(f * a2 + (1.f - f) * b2);
    o.w = f2bf(f * a3 + (1.f - f) * b3);
    ((ushort4*)(m + (size_t)wid * HDIM))[lane] = o;
}

// ------------------------------------------------------------------ launch

extern "C" void kernel_launch(void* const* d_in, const int* in_sizes, int n_in,
                              void* d_out, int out_size, void* d_ws, size_t ws_size,
                              hipStream_t stream) {
    (void)n_in; (void)out_size; (void)ws_size;
    const int N = N_NODES, E = E_EDGES;

    const float* x1; const float* x2; const int* ei1; const int* ei2;
    if (in_sizes[1] == 2 * E) {
        x1 = (const float*)d_in[0]; ei1 = (const int*)d_in[1];
        x2 = (const float*)d_in[2]; ei2 = (const int*)d_in[3];
    } else {
        x1 = (const float*)d_in[0]; x2 = (const float*)d_in[1];
        ei1 = (const int*)d_in[2]; ei2 = (const int*)d_in[3];
    }
    const float* W[2][4]; const float* Bv[2][4];
    int idx = 4;
    for (int br = 0; br < 2; br++)
        for (int l = 0; l < 4; l++) {
            W[br][l] = (const float*)d_in[idx++];
            Bv[br][l] = (const float*)d_in[idx++];
        }
    const float* w1W  = (const float*)d_in[20];
    const float* w1b  = (const float*)d_in[21];
    const float* w2W  = (const float*)d_in[22];
    const float* w2b  = (const float*)d_in[23];
    const float* finW = (const float*)d_in[24];
    const float* finb = (const float*)d_in[25];
    const float* outW = (const float*)d_in[26];
    const float* outb = (const float*)d_in[27];
    float* out = (float*)d_out;

    size_t off = 0;
    auto alloc = [&](size_t bytes) {
        void* p = (char*)d_ws + off;
        off = (off + bytes + 255) & ~(size_t)255;
        return p;
    };
    unsigned short* x1b = (unsigned short*)alloc((size_t)N * F_IN * 2);  // also fin-out t
    unsigned short* x2b = (unsigned short*)alloc((size_t)N * F_IN * 2);
    unsigned char*  g8  = (unsigned char*)alloc((size_t)N * HDIM);       // fp8 GEMM out
    unsigned short* mb_ = (unsigned short*)alloc((size_t)N * HDIM * 2);
    unsigned short* h1b = (unsigned short*)alloc((size_t)N * HDIM * 2);
    unsigned short* h2b = (unsigned short*)alloc((size_t)N * HDIM * 2);
    unsigned short* Wt[2][4];
    Wt[0][0] = (unsigned short*)alloc((size_t)HDIM * F_IN * 2);
    for (int l = 1; l < 4; l++) Wt[0][l] = (unsigned short*)alloc((size_t)HDIM * HDIM * 2);
    Wt[1][0] = (unsigned short*)alloc((size_t)HDIM * F_IN * 2);
    for (int l = 1; l < 4; l++) Wt[1][l] = (unsigned short*)alloc((size_t)HDIM * HDIM * 2);
    unsigned short* finWt = (unsigned short*)alloc((size_t)HDIM * HDIM * 2);
    unsigned short* outWt = (unsigned short*)alloc((size_t)128 * HDIM * 2);
    unsigned short* col1 = (unsigned short*)alloc((size_t)E * 2);
    unsigned short* col2 = (unsigned short*)alloc((size_t)E * 2);
    unsigned int* rec1 = (unsigned int*)alloc((size_t)E * 4);
    unsigned int* rec2 = (unsigned int*)alloc((size_t)E * 4);
    int* hist1  = (int*)alloc((size_t)NB1 * NBLK * 4);
    int* hist2  = (int*)alloc((size_t)NB1 * NBLK * 4);
    int* tot1   = (int*)alloc((size_t)NB1 * 4);
    int* tot2   = (int*)alloc((size_t)NB1 * 4);
    int* bs1    = (int*)alloc((size_t)(NB1 + 1) * 4);
    int* bs2    = (int*)alloc((size_t)(NB1 + 1) * 4);
    int* rp1    = (int*)alloc((size_t)(N + 1) * 4);
    int* rp2    = (int*)alloc((size_t)(N + 1) * 4);
    int* cnt1   = (int*)alloc((size_t)N * 4);
    int* cnt2   = (int*)alloc((size_t)N * 4);
    float* di1  = (float*)alloc((size_t)N * 4);
    float* di2  = (float*)alloc((size_t)N * 4);

    const int BLK = 256;
    int mtiles = (N + 127) / 128;                 // 391
    dim3 grid_h(HDIM / 128, mtiles);
    dim3 grid_o(1, mtiles);
    int agg_blocks = 2048;                        // 8192 persistent waves
    int gate_blocks = (N * 64 + BLK - 1) / BLK;

    // weight conversion (independent of CSR build)
    WPack wp;
    wp.d[0] = {W[0][0], Wt[0][0], F_IN, HDIM, HDIM};
    wp.d[1] = {W[0][1], Wt[0][1], HDIM, HDIM, HDIM};
    wp.d[2] = {W[0][2], Wt[0][2], HDIM, HDIM, HDIM};
    wp.d[3] = {W[0][3], Wt[0][3], HDIM, HDIM, HDIM};
    wp.d[4] = {W[1][0], Wt[1][0], F_IN, HDIM, HDIM};
    wp.d[5] = {W[1][1], Wt[1][1], HDIM, HDIM, HDIM};
    wp.d[6] = {W[1][2], Wt[1][2], HDIM, HDIM, HDIM};
    wp.d[7] = {W[1][3], Wt[1][3], HDIM, HDIM, HDIM};
    wp.d[8] = {finW, finWt, HDIM, HDIM, HDIM};
    wp.d[9] = {outW, outWt, HDIM, L_OUT, 128};
    k_wconv<<<dim3(512, 10), BLK, 0, stream>>>(wp);
    k_f2b2<<<2048, BLK, 0, stream>>>(x1, x2, x1b, x2b, N * F_IN / 8);

    // atomic-free CSR build (two-level counting sort), both branches
    k_hist<<<dim3(NBLK, 2), BLK, 0, stream>>>(ei1 + E, ei2 + E, hist1, hist2, E);
    k_scanb<<<dim3(NB1, 2), BLK, 0, stream>>>(hist1, hist2, tot1, tot2);
    k_bstart<<<dim3(1, 2), 512, 0, stream>>>(tot1, tot2, bs1, bs2, rp1, rp2, N, E);
    k_scatter<<<dim3(NBLK, 2), BLK, 0, stream>>>(ei1, ei1 + E, ei2, ei2 + E,
                                                 hist1, hist2, bs1, bs2, rec1, rec2, E);
    k_sort<<<dim3(NB1, 2), BLK, 0, stream>>>(rec1, rec2, bs1, bs2,
                                             cnt1, cnt2, rp1, rp2, col1, col2, N);
    k_dinv2<<<(2 * N + BLK - 1) / BLK, BLK, 0, stream>>>(cnt1, cnt2, di1, di2, N);

    // branch-sequential layers: GEMM -> agg immediately (g8 hot in L2)
    for (int br = 0; br < 2; br++) {
        const unsigned short* col = br ? col2 : col1;
        const int* rp = br ? rp2 : rp1;
        const float* di = br ? di2 : di1;
        const unsigned short* xb = br ? x2b : x1b;
        unsigned short* hb = br ? h2b : h1b;

        k_gemm<0><<<grid_h, BLK, 0, stream>>>(xb, Wt[br][0], nullptr, g8, N, F_IN, HDIM);
        k_agg<<<agg_blocks, BLK, 0, stream>>>(g8, rp, col, di, Bv[br][0], hb, N, 1);
        for (int l = 1; l <= 2; l++) {
            k_gemm<0><<<grid_h, BLK, 0, stream>>>(hb, Wt[br][l], nullptr, g8, N, HDIM, HDIM);
            k_agg<<<agg_blocks, BLK, 0, stream>>>(g8, rp, col, di, Bv[br][l], hb, N, 1);
        }
        k_gemm<0><<<grid_h, BLK, 0, stream>>>(hb, Wt[br][3], nullptr, g8, N, HDIM, HDIM);
        k_agg<<<agg_blocks, BLK, 0, stream>>>(g8, rp, col, di, Bv[br][3], hb, N, 0);
    }

    k_gate<<<gate_blocks, BLK, 0, stream>>>(h1b, h2b, w1W, w1b, w2W, w2b, mb_, N);
    k_gemm<1><<<grid_h, BLK, 0, stream>>>(mb_, finWt, finb, x1b, N, HDIM, HDIM);
    k_gemm<2><<<grid_o, BLK, 0, stream>>>(x1b, outWt, outb, out, N, HDIM, L_OUT);
}

// Round 15
// 869.945 us; speedup vs baseline: 1.1461x; 1.1461x over previous
//
#include <hip/hip_runtime.h>
#include <math.h>

#define N_NODES 50000
#define F_IN    512
#define HDIM    256
#define L_OUT   52
#define E_EDGES 1600000
#define NB1     391      // ceil(N/128) level-1 buckets (dst>>7)
#define EB      2048     // edges per chunk
#define NBLK    782      // ceil(E/EB)

typedef short short8 __attribute__((ext_vector_type(8)));
typedef unsigned short u16x8 __attribute__((ext_vector_type(8)));
typedef float f32x4 __attribute__((ext_vector_type(4)));
typedef float f32x2 __attribute__((ext_vector_type(2)));

__device__ __forceinline__ float bf2f(unsigned short u) {
    unsigned int x = ((unsigned int)u) << 16;
    return __builtin_bit_cast(float, x);
}
__device__ __forceinline__ unsigned short f2bf(float f) {
    unsigned int u = __builtin_bit_cast(unsigned int, f);
    return (unsigned short)((u + 0x7fffu + ((u >> 16) & 1u)) >> 16);
}
__device__ __forceinline__ unsigned char f2fp8(float f) {
    int pk = __builtin_amdgcn_cvt_pk_fp8_f32(f, 0.f, 0, false);
    return (unsigned char)(pk & 0xff);
}
__device__ __forceinline__ void gload16(const void* g, void* l) {
    __builtin_amdgcn_global_load_lds(
        (const __attribute__((address_space(1))) unsigned int*)(g),
        (__attribute__((address_space(3))) unsigned int*)(l), 16, 0, 0);
}

// ---------------- CSR build: atomic-free two-level counting sort ----------

__global__ __launch_bounds__(256) void k_hist(const int* __restrict__ d1, const int* __restrict__ d2,
                                              int* __restrict__ h1, int* __restrict__ h2, int E) {
    const int* D = blockIdx.y ? d2 : d1;
    int* H = blockIdx.y ? h2 : h1;
    __shared__ int h[NB1];
    for (int t = threadIdx.x; t < NB1; t += 256) h[t] = 0;
    __syncthreads();
    int base = blockIdx.x * EB;
#pragma unroll
    for (int k = 0; k < 8; k++) {
        int e = base + k * 256 + threadIdx.x;
        if (e < E) atomicAdd(&h[D[e] >> 7], 1);   // LDS atomic
    }
    __syncthreads();
    for (int t = threadIdx.x; t < NB1; t += 256)
        H[(size_t)t * NBLK + blockIdx.x] = h[t];
}

__global__ __launch_bounds__(256) void k_scanb(int* __restrict__ h1, int* __restrict__ h2,
                                               int* __restrict__ t1, int* __restrict__ t2) {
    int* H = blockIdx.y ? h2 : h1;
    int* T = blockIdx.y ? t2 : t1;
    int b = blockIdx.x;
    __shared__ int s[256];
    int carry = 0;
    for (int base = 0; base < NBLK; base += 256) {
        int i = base + threadIdx.x;
        int v = (i < NBLK) ? H[(size_t)b * NBLK + i] : 0;
        s[threadIdx.x] = v;
        __syncthreads();
        for (int off = 1; off < 256; off <<= 1) {
            int t = (threadIdx.x >= off) ? s[threadIdx.x - off] : 0;
            __syncthreads();
            s[threadIdx.x] += t;
            __syncthreads();
        }
        if (i < NBLK) H[(size_t)b * NBLK + i] = carry + s[threadIdx.x] - v;
        int ct = s[255];
        __syncthreads();
        carry += ct;
    }
    if (threadIdx.x == 0) T[b] = carry;
}

__global__ __launch_bounds__(512) void k_bstart(const int* __restrict__ t1, const int* __restrict__ t2,
                                                int* __restrict__ b1, int* __restrict__ b2,
                                                int* __restrict__ rp1, int* __restrict__ rp2,
                                                int N, int E) {
    const int* T = blockIdx.y ? t2 : t1;
    int* BS = blockIdx.y ? b2 : b1;
    int* RP = blockIdx.y ? rp2 : rp1;
    __shared__ int s[512];
    int v = (threadIdx.x < NB1) ? T[threadIdx.x] : 0;
    s[threadIdx.x] = v;
    __syncthreads();
    for (int off = 1; off < 512; off <<= 1) {
        int t = (threadIdx.x >= off) ? s[threadIdx.x - off] : 0;
        __syncthreads();
        s[threadIdx.x] += t;
        __syncthreads();
    }
    if (threadIdx.x < NB1) BS[threadIdx.x] = s[threadIdx.x] - v;
    if (threadIdx.x == 0) { BS[NB1] = E; RP[N] = E; }
}

__global__ __launch_bounds__(256) void k_scatter(const int* __restrict__ s1, const int* __restrict__ d1,
                                                 const int* __restrict__ s2, const int* __restrict__ d2,
                                                 const int* __restrict__ h1, const int* __restrict__ h2,
                                                 const int* __restrict__ b1, const int* __restrict__ b2,
                                                 unsigned int* __restrict__ r1, unsigned int* __restrict__ r2,
                                                 int E) {
    int br = blockIdx.y;
    const int* S = br ? s2 : s1;
    const int* D = br ? d2 : d1;
    const int* H = br ? h2 : h1;
    const int* BS = br ? b2 : b1;
    unsigned int* R = br ? r2 : r1;
    __shared__ int cur[NB1];
    for (int t = threadIdx.x; t < NB1; t += 256)
        cur[t] = BS[t] + H[(size_t)t * NBLK + blockIdx.x];
    __syncthreads();
    int base = blockIdx.x * EB;
#pragma unroll
    for (int k = 0; k < 8; k++) {
        int e = base + k * 256 + threadIdx.x;
        if (e < E) {
            int d = D[e];
            int p = atomicAdd(&cur[d >> 7], 1);   // LDS atomic, block-exclusive range
            R[p] = (unsigned int)(S[e] & 0xFFFF) | ((unsigned int)d << 16);
        }
    }
}

__global__ __launch_bounds__(256) void k_sort(const unsigned int* __restrict__ r1,
                                              const unsigned int* __restrict__ r2,
                                              const int* __restrict__ b1, const int* __restrict__ b2,
                                              int* __restrict__ c1, int* __restrict__ c2,
                                              int* __restrict__ rp1, int* __restrict__ rp2,
                                              unsigned short* __restrict__ col1,
                                              unsigned short* __restrict__ col2, int N) {
    int br = blockIdx.y;
    const unsigned int* R = br ? r2 : r1;
    const int* BS = br ? b2 : b1;
    int* CNT = br ? c2 : c1;
    int* RP = br ? rp2 : rp1;
    unsigned short* COL = br ? col2 : col1;
    int b = blockIdx.x;
    int s = BS[b], sz = BS[b + 1] - s;
    __shared__ int h[128], sc[128], cur[128];
    if (threadIdx.x < 128) h[threadIdx.x] = 0;
    __syncthreads();
    for (int i = s + threadIdx.x; i < s + sz; i += 256)
        atomicAdd(&h[(R[i] >> 16) & 127], 1);
    __syncthreads();
    if (threadIdx.x < 128) sc[threadIdx.x] = h[threadIdx.x];
    __syncthreads();
    for (int off = 1; off < 128; off <<= 1) {
        int t = 0;
        if (threadIdx.x < 128 && threadIdx.x >= off) t = sc[threadIdx.x - off];
        __syncthreads();
        if (threadIdx.x < 128) sc[threadIdx.x] += t;
        __syncthreads();
    }
    if (threadIdx.x < 128) {
        int excl = sc[threadIdx.x] - h[threadIdx.x];
        cur[threadIdx.x] = excl;
        int node = b * 128 + threadIdx.x;
        if (node < N) { CNT[node] = h[threadIdx.x]; RP[node] = s + excl; }
    }
    __syncthreads();
    for (int i = s + threadIdx.x; i < s + sz; i += 256) {
        unsigned int r = R[i];
        int low = (r >> 16) & 127;
        int p = atomicAdd(&cur[low], 1);          // LDS atomic
        COL[s + p] = (unsigned short)(r & 0xFFFFu);
    }
}

// ------------------------------------------------------------- conversions

__global__ void k_dinv2(const int* __restrict__ c1, const int* __restrict__ c2,
                        float* __restrict__ v1, float* __restrict__ v2, int n) {
    int i = blockIdx.x * blockDim.x + threadIdx.x;
    if (i < n) v1[i] = rsqrtf((float)(c1[i] + 1));
    else if (i < 2 * n) v2[i - n] = rsqrtf((float)(c2[i - n] + 1));
}

struct WDesc { const float* in; unsigned short* out; int K; int N; int Npad; };
struct WPack { WDesc d[10]; };

__global__ void k_wconv(WPack p) {
    WDesc w = p.d[blockIdx.y];
    int total = w.K * w.Npad;
    int idx = blockIdx.x * 256 + threadIdx.x;
    if (idx >= total) return;
    int n = idx / w.K, k = idx - n * w.K;
    w.out[idx] = (n < w.N) ? f2bf(w.in[(size_t)k * w.N + n]) : (unsigned short)0;
}

// ------- aggregation (R12-exact): wave/node, lane-halves = even/odd streams,
//         16-deep 8B fp8 gathers; weight = dinv[col]*dinv[wid].

__global__ void k_agg(const unsigned char* __restrict__ g, const int* __restrict__ rowptr,
                      const unsigned short* __restrict__ col,
                      const float* __restrict__ dinv,
                      const float* __restrict__ bias, unsigned short* __restrict__ out,
                      int n, int do_relu) {
    int gtid = blockIdx.x * blockDim.x + threadIdx.x;
    int wid = gtid >> 6;
    if (wid >= n) return;
    int lane = threadIdx.x & 63;
    int half = lane >> 5;   // even/odd neighbor stream
    int fl = lane & 31;     // 8B slice of the 256B fp8 row

    float di = dinv[wid];

    float a[8];
#pragma unroll
    for (int k = 0; k < 8; k++) a[k] = 0.f;

    int r0 = rowptr[wid], r1 = rowptr[wid + 1];
    int base = r0;

    for (; base + 32 <= r1; base += 32) {
        int c[16]; float w[16]; uint2 v[16];
#pragma unroll
        for (int t = 0; t < 16; t++) c[t] = col[base + 2 * t + half];
#pragma unroll
        for (int t = 0; t < 16; t++) w[t] = dinv[c[t]];
#pragma unroll
        for (int t = 0; t < 16; t++)
            v[t] = ((const uint2*)(g + (size_t)c[t] * HDIM))[fl];
#pragma unroll
        for (int t = 0; t < 16; t++) {
            float wt = w[t] * di;
            f32x2 p0 = __builtin_amdgcn_cvt_pk_f32_fp8((int)v[t].x, false);
            f32x2 p1 = __builtin_amdgcn_cvt_pk_f32_fp8((int)v[t].x, true);
            f32x2 p2 = __builtin_amdgcn_cvt_pk_f32_fp8((int)v[t].y, false);
            f32x2 p3 = __builtin_amdgcn_cvt_pk_f32_fp8((int)v[t].y, true);
            a[0] = fmaf(p0[0], wt, a[0]); a[1] = fmaf(p0[1], wt, a[1]);
            a[2] = fmaf(p1[0], wt, a[2]); a[3] = fmaf(p1[1], wt, a[3]);
            a[4] = fmaf(p2[0], wt, a[4]); a[5] = fmaf(p2[1], wt, a[5]);
            a[6] = fmaf(p3[0], wt, a[6]); a[7] = fmaf(p3[1], wt, a[7]);
        }
    }
    for (; base + 16 <= r1; base += 16) {
        int c[8]; float w[8]; uint2 v[8];
#pragma unroll
        for (int t = 0; t < 8; t++) c[t] = col[base + 2 * t + half];
#pragma unroll
        for (int t = 0; t < 8; t++) w[t] = dinv[c[t]];
#pragma unroll
        for (int t = 0; t < 8; t++)
            v[t] = ((const uint2*)(g + (size_t)c[t] * HDIM))[fl];
#pragma unroll
        for (int t = 0; t < 8; t++) {
            float wt = w[t] * di;
            f32x2 p0 = __builtin_amdgcn_cvt_pk_f32_fp8((int)v[t].x, false);
            f32x2 p1 = __builtin_amdgcn_cvt_pk_f32_fp8((int)v[t].x, true);
            f32x2 p2 = __builtin_amdgcn_cvt_pk_f32_fp8((int)v[t].y, false);
            f32x2 p3 = __builtin_amdgcn_cvt_pk_f32_fp8((int)v[t].y, true);
            a[0] = fmaf(p0[0], wt, a[0]); a[1] = fmaf(p0[1], wt, a[1]);
            a[2] = fmaf(p1[0], wt, a[2]); a[3] = fmaf(p1[1], wt, a[3]);
            a[4] = fmaf(p2[0], wt, a[4]); a[5] = fmaf(p2[1], wt, a[5]);
            a[6] = fmaf(p3[0], wt, a[6]); a[7] = fmaf(p3[1], wt, a[7]);
        }
    }
    if (base < r1) {  // remainder 1..15, zero-weight padding
        int c[8]; float w[8]; uint2 v[8];
#pragma unroll
        for (int t = 0; t < 8; t++) {
            int idx = base + 2 * t + half;
            int ok = idx < r1;
            c[t] = col[ok ? idx : r0];
            w[t] = ok ? dinv[c[t]] : 0.f;
        }
#pragma unroll
        for (int t = 0; t < 8; t++)
            v[t] = ((const uint2*)(g + (size_t)c[t] * HDIM))[fl];
#pragma unroll
        for (int t = 0; t < 8; t++) {
            float wt = w[t] * di;
            f32x2 p0 = __builtin_amdgcn_cvt_pk_f32_fp8((int)v[t].x, false);
            f32x2 p1 = __builtin_amdgcn_cvt_pk_f32_fp8((int)v[t].x, true);
            f32x2 p2 = __builtin_amdgcn_cvt_pk_f32_fp8((int)v[t].y, false);
            f32x2 p3 = __builtin_amdgcn_cvt_pk_f32_fp8((int)v[t].y, true);
            a[0] = fmaf(p0[0], wt, a[0]); a[1] = fmaf(p0[1], wt, a[1]);
            a[2] = fmaf(p1[0], wt, a[2]); a[3] = fmaf(p1[1], wt, a[3]);
            a[4] = fmaf(p2[0], wt, a[4]); a[5] = fmaf(p2[1], wt, a[5]);
            a[6] = fmaf(p3[0], wt, a[6]); a[7] = fmaf(p3[1], wt, a[7]);
        }
    }

#pragma unroll
    for (int k = 0; k < 8; k++) a[k] += __shfl_xor(a[k], 32);

    float w0 = di * di;
    uint2 sv = ((const uint2*)(g + (size_t)wid * HDIM))[fl];
    f32x2 s0 = __builtin_amdgcn_cvt_pk_f32_fp8((int)sv.x, false);
    f32x2 s1 = __builtin_amdgcn_cvt_pk_f32_fp8((int)sv.x, true);
    f32x2 s2 = __builtin_amdgcn_cvt_pk_f32_fp8((int)sv.y, false);
    f32x2 s3 = __builtin_amdgcn_cvt_pk_f32_fp8((int)sv.y, true);
    float sf[8] = {s0[0], s0[1], s1[0], s1[1], s2[0], s2[1], s3[0], s3[1]};
    u16x8 o;
#pragma unroll
    for (int k = 0; k < 8; k++) {
        float x = fmaf(sf[k], w0, a[k]) + bias[fl * 8 + k];
        if (do_relu) x = fmaxf(x, 0.f);
        o[k] = f2bf(x);
    }
    if (half == 0)
        ((u16x8*)(out + (size_t)wid * HDIM))[fl] = o;
}

// --------------------------------------------------- bf16 MFMA GEMM 128x128
// EPI 0: raw -> fp8 C.  EPI 1: bias+relu -> bf16.  EPI 2: bias+sigmoid -> fp32.

template <int EPI>
__global__ __launch_bounds__(256) void k_gemm(const unsigned short* __restrict__ A,
                                              const unsigned short* __restrict__ Bt,
                                              const float* __restrict__ bias,
                                              void* __restrict__ Cout,
                                              int M, int K, int Nc) {
    __shared__ __align__(16) unsigned short As[128 * 32];
    __shared__ __align__(16) unsigned short Bs[128 * 32];
    int tid = threadIdx.x;
    int wid = tid >> 6, lane = tid & 63;
    int wr = wid >> 1, wc = wid & 1;
    int mb = blockIdx.y * 128, nb = blockIdx.x * 128;

    int sr = tid >> 2;
    int ssl = (tid & 3) ^ ((sr >> 1) & 3);
    int ar0 = mb + sr;      if (ar0 > M - 1) ar0 = M - 1;
    int ar1 = mb + sr + 64; if (ar1 > M - 1) ar1 = M - 1;
    const unsigned short* gA0 = A + (size_t)ar0 * K + ssl * 8;
    const unsigned short* gA1 = A + (size_t)ar1 * K + ssl * 8;
    const unsigned short* gB0 = Bt + (size_t)(nb + sr) * K + ssl * 8;
    const unsigned short* gB1 = Bt + (size_t)(nb + sr + 64) * K + ssl * 8;
    unsigned short* ldsA = As + tid * 8;
    unsigned short* ldsB = Bs + tid * 8;

    f32x4 acc[4][4];
#pragma unroll
    for (int m = 0; m < 4; m++)
#pragma unroll
        for (int n = 0; n < 4; n++) acc[m][n] = (f32x4){0.f, 0.f, 0.f, 0.f};

    int l15 = lane & 15, ks = lane >> 4;

    for (int k0 = 0; k0 < K; k0 += 32) {
        gload16(gA0 + k0, ldsA);
        gload16(gA1 + k0, ldsA + 2048);
        gload16(gB0 + k0, ldsB);
        gload16(gB1 + k0, ldsB + 2048);
        __syncthreads();

        short8 af[4], bfr[4];
#pragma unroll
        for (int m = 0; m < 4; m++) {
            int row = wr * 64 + m * 16 + l15;
            int slot = ks ^ ((row >> 1) & 3);
            af[m] = *(const short8*)((const char*)As + row * 64 + slot * 16);
        }
#pragma unroll
        for (int n = 0; n < 4; n++) {
            int row = wc * 64 + n * 16 + l15;
            int slot = ks ^ ((row >> 1) & 3);
            bfr[n] = *(const short8*)((const char*)Bs + row * 64 + slot * 16);
        }
#pragma unroll
        for (int m = 0; m < 4; m++)
#pragma unroll
            for (int n = 0; n < 4; n++)
                acc[m][n] = __builtin_amdgcn_mfma_f32_16x16x32_bf16(af[m], bfr[n], acc[m][n], 0, 0, 0);
        __syncthreads();
    }

    int lq = lane >> 4;
#pragma unroll
    for (int m = 0; m < 4; m++) {
#pragma unroll
        for (int n = 0; n < 4; n++) {
            int gcol = nb + wc * 64 + n * 16 + l15;
#pragma unroll
            for (int r = 0; r < 4; r++) {
                int grow = mb + wr * 64 + m * 16 + lq * 4 + r;
                if (grow >= M) continue;
                float v = acc[m][n][r];
                if (EPI == 0) {
                    ((unsigned char*)Cout)[(size_t)grow * Nc + gcol] = f2fp8(v);
                } else if (EPI == 1) {
                    v += bias[gcol];
                    v = fmaxf(v, 0.f);
                    ((unsigned short*)Cout)[(size_t)grow * Nc + gcol] = f2bf(v);
                } else {
                    if (gcol < Nc) {
                        v += bias[gcol];
                        v = 1.f / (1.f + expf(-v));
                        ((float*)Cout)[(size_t)grow * Nc + gcol] = v;
                    }
                }
            }
        }
    }
}

// -------------------- layer-1 GEMM: A fp32 DMA-staged, converted on read
// A32: [M][K] fp32 (x input). fp8 output, no bias. Fuses the old f2b2 pass.

__global__ __launch_bounds__(256) void k_gemm_l1(const float* __restrict__ A32,
                                                 const unsigned short* __restrict__ Bt,
                                                 unsigned char* __restrict__ Cout,
                                                 int M, int K, int Nc) {
    __shared__ __align__(16) float AsF[128 * 32];          // 16KB, 8x16B slots/row
    __shared__ __align__(16) unsigned short Bs[128 * 32];  // 8KB
    int tid = threadIdx.x;
    int wid = tid >> 6, lane = tid & 63;
    int wr = wid >> 1, wc = wid & 1;
    int mb = blockIdx.y * 128, nb = blockIdx.x * 128;

    int sr = tid >> 2;
    int ssl = (tid & 3) ^ ((sr >> 1) & 3);
    const unsigned short* gB0 = Bt + (size_t)(nb + sr) * K + ssl * 8;
    const unsigned short* gB1 = Bt + (size_t)(nb + sr + 64) * K + ssl * 8;
    unsigned short* ldsB = Bs + tid * 8;

    // A staging: 4 rounds x 16B. L = r*256+tid; row=L>>3, slot=L&7.
    // source chunk pre-swizzled: srcc = slot ^ (row&7) so swizzled read is linear.
    int arow[4], asrc[4];
#pragma unroll
    for (int r = 0; r < 4; r++) {
        int L = r * 256 + tid;
        int row = L >> 3, slot = L & 7;
        int ar = mb + row; if (ar > M - 1) ar = M - 1;
        arow[r] = ar;
        asrc[r] = (slot ^ (row & 7)) * 4;   // fp32 element offset within K-step
    }

    f32x4 acc[4][4];
#pragma unroll
    for (int m = 0; m < 4; m++)
#pragma unroll
        for (int n = 0; n < 4; n++) acc[m][n] = (f32x4){0.f, 0.f, 0.f, 0.f};

    int l15 = lane & 15, ks = lane >> 4;

    for (int k0 = 0; k0 < K; k0 += 32) {
#pragma unroll
        for (int r = 0; r < 4; r++)
            gload16(&A32[(size_t)arow[r] * K + k0 + asrc[r]],
                    (char*)AsF + (r * 256 + tid) * 16);
        gload16(gB0 + k0, ldsB);
        gload16(gB1 + k0, ldsB + 2048);
        __syncthreads();

        short8 af[4], bfr[4];
#pragma unroll
        for (int m = 0; m < 4; m++) {
            int row = wr * 64 + m * 16 + l15;
            int rs = row & 7;
            const char* rb = (const char*)AsF + row * 128;
            float4 fa = *(const float4*)(rb + (((2 * ks) ^ rs) * 16));
            float4 fb = *(const float4*)(rb + (((2 * ks + 1) ^ rs) * 16));
            short8 t;
            t[0] = (short)f2bf(fa.x); t[1] = (short)f2bf(fa.y);
            t[2] = (short)f2bf(fa.z); t[3] = (short)f2bf(fa.w);
            t[4] = (short)f2bf(fb.x); t[5] = (short)f2bf(fb.y);
            t[6] = (short)f2bf(fb.z); t[7] = (short)f2bf(fb.w);
            af[m] = t;
        }
#pragma unroll
        for (int n = 0; n < 4; n++) {
            int row = wc * 64 + n * 16 + l15;
            int slot = ks ^ ((row >> 1) & 3);
            bfr[n] = *(const short8*)((const char*)Bs + row * 64 + slot * 16);
        }
#pragma unroll
        for (int m = 0; m < 4; m++)
#pragma unroll
            for (int n = 0; n < 4; n++)
                acc[m][n] = __builtin_amdgcn_mfma_f32_16x16x32_bf16(af[m], bfr[n], acc[m][n], 0, 0, 0);
        __syncthreads();
    }

    int lq = lane >> 4;
#pragma unroll
    for (int m = 0; m < 4; m++) {
#pragma unroll
        for (int n = 0; n < 4; n++) {
            int gcol = nb + wc * 64 + n * 16 + l15;
#pragma unroll
            for (int r = 0; r < 4; r++) {
                int grow = mb + wr * 64 + m * 16 + lq * 4 + r;
                if (grow >= M) continue;
                Cout[(size_t)grow * Nc + gcol] = f2fp8(acc[m][n][r]);
            }
        }
    }
}

// ------------------------------------------------------------- gate fusion

__global__ void k_gate(const unsigned short* __restrict__ h1, const unsigned short* __restrict__ h2,
                       const float* __restrict__ w1, const float* __restrict__ w1b,
                       const float* __restrict__ w2, const float* __restrict__ w2b,
                       unsigned short* __restrict__ m, int n) {
    int gtid = blockIdx.x * blockDim.x + threadIdx.x;
    int wid = gtid >> 6;
    int lane = threadIdx.x & 63;
    if (wid >= n) return;
    ushort4 av = ((const ushort4*)(h1 + (size_t)wid * HDIM))[lane];
    ushort4 bv = ((const ushort4*)(h2 + (size_t)wid * HDIM))[lane];
    float4 wa = ((const float4*)w1)[lane];
    float4 wb = ((const float4*)w2)[lane];
    float a0 = bf2f(av.x), a1 = bf2f(av.y), a2 = bf2f(av.z), a3 = bf2f(av.w);
    float b0 = bf2f(bv.x), b1 = bf2f(bv.y), b2 = bf2f(bv.z), b3 = bf2f(bv.w);
    float d1 = a0 * wa.x + a1 * wa.y + a2 * wa.z + a3 * wa.w;
    float d2 = b0 * wb.x + b1 * wb.y + b2 * wb.z + b3 * wb.w;
    for (int off = 32; off > 0; off >>= 1) {
        d1 += __shfl_xor(d1, off);
        d2 += __shfl_xor(d2, off);
    }
    float f1 = 1.f / (1.f + expf(-(d1 + w1b[0])));
    float f2 = 1.f / (1.f + expf(-(d2 + w2b[0])));
    float f = f1 / (f1 + f2);
    ushort4 o;
    o.x = f2bf(f * a0 + (1.f - f) * b0);
    o.y = f2bf(f * a1 + (1.f - f) * b1);
    o.z = f2bf(f * a2 + (1.f - f) * b2);
    o.w = f2bf(f * a3 + (1.f - f) * b3);
    ((ushort4*)(m + (size_t)wid * HDIM))[lane] = o;
}

// ------------------------------------------------------------------ launch

extern "C" void kernel_launch(void* const* d_in, const int* in_sizes, int n_in,
                              void* d_out, int out_size, void* d_ws, size_t ws_size,
                              hipStream_t stream) {
    (void)n_in; (void)out_size; (void)ws_size;
    const int N = N_NODES, E = E_EDGES;

    const float* x1; const float* x2; const int* ei1; const int* ei2;
    if (in_sizes[1] == 2 * E) {
        x1 = (const float*)d_in[0]; ei1 = (const int*)d_in[1];
        x2 = (const float*)d_in[2]; ei2 = (const int*)d_in[3];
    } else {
        x1 = (const float*)d_in[0]; x2 = (const float*)d_in[1];
        ei1 = (const int*)d_in[2]; ei2 = (const int*)d_in[3];
    }
    const float* W[2][4]; const float* Bv[2][4];
    int idx = 4;
    for (int br = 0; br < 2; br++)
        for (int l = 0; l < 4; l++) {
            W[br][l] = (const float*)d_in[idx++];
            Bv[br][l] = (const float*)d_in[idx++];
        }
    const float* w1W  = (const float*)d_in[20];
    const float* w1b  = (const float*)d_in[21];
    const float* w2W  = (const float*)d_in[22];
    const float* w2b  = (const float*)d_in[23];
    const float* finW = (const float*)d_in[24];
    const float* finb = (const float*)d_in[25];
    const float* outW = (const float*)d_in[26];
    const float* outb = (const float*)d_in[27];
    float* out = (float*)d_out;

    size_t off = 0;
    auto alloc = [&](size_t bytes) {
        void* p = (char*)d_ws + off;
        off = (off + bytes + 255) & ~(size_t)255;
        return p;
    };
    unsigned char*  g8  = (unsigned char*)alloc((size_t)N * HDIM);       // fp8 GEMM out
    unsigned short* mb_ = (unsigned short*)alloc((size_t)N * HDIM * 2);  // gate out m
    unsigned short* tb_ = (unsigned short*)alloc((size_t)N * HDIM * 2);  // fin out t
    unsigned short* h1b = (unsigned short*)alloc((size_t)N * HDIM * 2);
    unsigned short* h2b = (unsigned short*)alloc((size_t)N * HDIM * 2);
    unsigned short* Wt[2][4];
    Wt[0][0] = (unsigned short*)alloc((size_t)HDIM * F_IN * 2);
    for (int l = 1; l < 4; l++) Wt[0][l] = (unsigned short*)alloc((size_t)HDIM * HDIM * 2);
    Wt[1][0] = (unsigned short*)alloc((size_t)HDIM * F_IN * 2);
    for (int l = 1; l < 4; l++) Wt[1][l] = (unsigned short*)alloc((size_t)HDIM * HDIM * 2);
    unsigned short* finWt = (unsigned short*)alloc((size_t)HDIM * HDIM * 2);
    unsigned short* outWt = (unsigned short*)alloc((size_t)128 * HDIM * 2);
    unsigned short* col1 = (unsigned short*)alloc((size_t)E * 2);
    unsigned short* col2 = (unsigned short*)alloc((size_t)E * 2);
    unsigned int* rec1 = (unsigned int*)alloc((size_t)E * 4);
    unsigned int* rec2 = (unsigned int*)alloc((size_t)E * 4);
    int* hist1  = (int*)alloc((size_t)NB1 * NBLK * 4);
    int* hist2  = (int*)alloc((size_t)NB1 * NBLK * 4);
    int* tot1   = (int*)alloc((size_t)NB1 * 4);
    int* tot2   = (int*)alloc((size_t)NB1 * 4);
    int* bs1    = (int*)alloc((size_t)(NB1 + 1) * 4);
    int* bs2    = (int*)alloc((size_t)(NB1 + 1) * 4);
    int* rp1    = (int*)alloc((size_t)(N + 1) * 4);
    int* rp2    = (int*)alloc((size_t)(N + 1) * 4);
    int* cnt1   = (int*)alloc((size_t)N * 4);
    int* cnt2   = (int*)alloc((size_t)N * 4);
    float* di1  = (float*)alloc((size_t)N * 4);
    float* di2  = (float*)alloc((size_t)N * 4);

    const int BLK = 256;
    int nwaves_grid = (N * 64 + BLK - 1) / BLK;   // 12500
    int mtiles = (N + 127) / 128;                 // 391
    dim3 grid_h(HDIM / 128, mtiles);
    dim3 grid_o(1, mtiles);

    // weight conversion (independent of CSR build)
    WPack wp;
    wp.d[0] = {W[0][0], Wt[0][0], F_IN, HDIM, HDIM};
    wp.d[1] = {W[0][1], Wt[0][1], HDIM, HDIM, HDIM};
    wp.d[2] = {W[0][2], Wt[0][2], HDIM, HDIM, HDIM};
    wp.d[3] = {W[0][3], Wt[0][3], HDIM, HDIM, HDIM};
    wp.d[4] = {W[1][0], Wt[1][0], F_IN, HDIM, HDIM};
    wp.d[5] = {W[1][1], Wt[1][1], HDIM, HDIM, HDIM};
    wp.d[6] = {W[1][2], Wt[1][2], HDIM, HDIM, HDIM};
    wp.d[7] = {W[1][3], Wt[1][3], HDIM, HDIM, HDIM};
    wp.d[8] = {finW, finWt, HDIM, HDIM, HDIM};
    wp.d[9] = {outW, outWt, HDIM, L_OUT, 128};
    k_wconv<<<dim3(512, 10), BLK, 0, stream>>>(wp);

    // atomic-free CSR build (two-level counting sort), both branches
    k_hist<<<dim3(NBLK, 2), BLK, 0, stream>>>(ei1 + E, ei2 + E, hist1, hist2, E);
    k_scanb<<<dim3(NB1, 2), BLK, 0, stream>>>(hist1, hist2, tot1, tot2);
    k_bstart<<<dim3(1, 2), 512, 0, stream>>>(tot1, tot2, bs1, bs2, rp1, rp2, N, E);
    k_scatter<<<dim3(NBLK, 2), BLK, 0, stream>>>(ei1, ei1 + E, ei2, ei2 + E,
                                                 hist1, hist2, bs1, bs2, rec1, rec2, E);
    k_sort<<<dim3(NB1, 2), BLK, 0, stream>>>(rec1, rec2, bs1, bs2,
                                             cnt1, cnt2, rp1, rp2, col1, col2, N);
    k_dinv2<<<(2 * N + BLK - 1) / BLK, BLK, 0, stream>>>(cnt1, cnt2, di1, di2, N);

    // branch-sequential layers: GEMM -> agg immediately (g8 hot in L2)
    for (int br = 0; br < 2; br++) {
        const unsigned short* col = br ? col2 : col1;
        const int* rp = br ? rp2 : rp1;
        const float* di = br ? di2 : di1;
        const float* x = br ? x2 : x1;
        unsigned short* hb = br ? h2b : h1b;

        // layer 1: A fp32 via DMA, converted at fragment read (f2b2 fused)
        k_gemm_l1<<<grid_h, BLK, 0, stream>>>(x, Wt[br][0], g8, N, F_IN, HDIM);
        k_agg<<<nwaves_grid, BLK, 0, stream>>>(g8, rp, col, di, Bv[br][0], hb, N, 1);
        for (int l = 1; l <= 2; l++) {
            k_gemm<0><<<grid_h, BLK, 0, stream>>>(hb, Wt[br][l], nullptr, g8, N, HDIM, HDIM);
            k_agg<<<nwaves_grid, BLK, 0, stream>>>(g8, rp, col, di, Bv[br][l], hb, N, 1);
        }
        k_gemm<0><<<grid_h, BLK, 0, stream>>>(hb, Wt[br][3], nullptr, g8, N, HDIM, HDIM);
        k_agg<<<nwaves_grid, BLK, 0, stream>>>(g8, rp, col, di, Bv[br][3], hb, N, 0);
    }

    k_gate<<<nwaves_grid, BLK, 0, stream>>>(h1b, h2b, w1W, w1b, w2W, w2b, mb_, N);
    k_gemm<1><<<grid_h, BLK, 0, stream>>>(mb_, finWt, finb, tb_, N, HDIM, HDIM);
    k_gemm<2><<<grid_o, BLK, 0, stream>>>(tb_, outWt, outb, out, N, HDIM, L_OUT);
}